// Round 7
// baseline (350.322 us; speedup 1.0000x reference)
//
#include <hip/hip_runtime.h>
#include <cstdint>

#define Hq 16
#define HKVn 8
#define DHn 128
#define Tn 2048
#define Bn 2
#define Dm 2048
#define BT (Bn*Tn)   // 4096

typedef __attribute__((ext_vector_type(8))) short bfrag8;   // 8 bf16 (4 VGPRs)
typedef __attribute__((ext_vector_type(4))) float facc4;    // 4 fp32 acc
typedef __attribute__((ext_vector_type(4))) _Float16 f16x4; // 4 fp16 (2 VGPRs)
typedef __attribute__((ext_vector_type(8))) _Float16 f16x8; // 8 fp16 (4 VGPRs)
typedef __attribute__((ext_vector_type(8))) unsigned short us8;

__device__ __forceinline__ unsigned short f2bf(float f) {
    union { float f; unsigned int u; } v; v.f = f;
    unsigned int u = v.u;
    unsigned int r = (u + 0x7FFFu + ((u >> 16) & 1u)) >> 16;
    return (unsigned short)r;
}
__device__ __forceinline__ float bf2f(unsigned short u) {
    union { unsigned int u; float f; } v; v.u = ((unsigned int)u) << 16;
    return v.f;
}

// ---------------- fused fp32 -> bf16 convert + RoPE cos/sin LUT ----------------
__global__ __launch_bounds__(256) void cvt_all(const float* __restrict__ x,
                                               const float* __restrict__ wq,
                                               const float* __restrict__ wk,
                                               const float* __restrict__ wv,
                                               const float* __restrict__ wo,
                                               unsigned short* __restrict__ x_bf,
                                               unsigned short* __restrict__ wqkv_bf,
                                               unsigned short* __restrict__ wo_bf,
                                               float* __restrict__ lut) {
    int i = blockIdx.x * 256 + threadIdx.x;   // float4 index, total 5242880
    if (i >= 5242880) {
        int ii = i - 5242880;                 // 0..131071
        int t = ii >> 6, d = ii & 63;
        float fr = exp2f(-(float)d * 0.3114307588956902f);
        float ang = (float)t * fr;
        float sv, cv;
        __sincosf(ang, &sv, &cv);
        lut[t * 128 + d] = cv;
        lut[t * 128 + 64 + d] = sv;
        return;
    }
    const float4* src; ushort4* dst;
    if (i < 2097152)      { src = (const float4*)x  + i;            dst = (ushort4*)x_bf + i; }
    else if (i < 3145728) { src = (const float4*)wq + (i-2097152);  dst = (ushort4*)wqkv_bf + (i-2097152); }
    else if (i < 3670016) { src = (const float4*)wk + (i-3145728);  dst = (ushort4*)wqkv_bf + 1048576 + (i-3145728); }
    else if (i < 4194304) { src = (const float4*)wv + (i-3670016);  dst = (ushort4*)wqkv_bf + 1572864 + (i-3670016); }
    else                  { src = (const float4*)wo + (i-4194304);  dst = (ushort4*)wo_bf + (i-4194304); }
    float4 v = *src;
    ushort4 y;
    y.x = f2bf(v.x); y.y = f2bf(v.y); y.z = f2bf(v.z); y.w = f2bf(v.w);
    *dst = y;
}

// K tiled-layout element offset within a (b,hkv) plane (attn-kernel K layout).
__device__ __forceinline__ size_t koff_tiled(int t, int d) {
    int kc = (t >> 4) & 3, l15 = t & 15;
    int f = d >> 5, qd = (d >> 3) & 3, j = d & 7;
    return (size_t)(t >> 6) * 8192 + ((((kc * 4 + f) * 64 + qd * 16 + l15) << 3) + j);
}

// ---------------- staging helpers (linear LDS dest, inverse-XOR-swizzled source) -----
__device__ __forceinline__ void stage_half(const unsigned short* __restrict__ g0,
                                           int rowBase, int k0, char* region, int h, int tid) {
#pragma unroll
    for (int s = 0; s < 2; s++) {
        int c = h * 1024 + s * 512 + tid;        // chunk index (16B units)
        int r = c >> 3;
        int kk = (c & 7) ^ (r & 7);
        const unsigned short* g = g0 + (size_t)(rowBase + r) * 2048 + k0 + kk * 8;
        __builtin_amdgcn_global_load_lds((const __attribute__((address_space(1))) void*)g,
            (__attribute__((address_space(3))) void*)(region + c * 16), 16, 0, 0);
    }
}

// 64-row half-tile for the 128^2 out-proj kernel (256 threads, 2 loads/thread)
__device__ __forceinline__ void stage_half_bt(const unsigned short* __restrict__ g0,
                                              int rowBase, int k0, char* region, int h,
                                              int tid, int K) {
#pragma unroll
    for (int s = 0; s < 2; s++) {
        int c = h * 512 + s * 256 + tid;         // chunk index within 16KB region
        int r = c >> 3;
        int kk = (c & 7) ^ (r & 7);
        const unsigned short* g = g0 + (size_t)(rowBase + r) * K + k0 + kk * 8;
        __builtin_amdgcn_global_load_lds((const __attribute__((address_space(1))) void*)g,
            (__attribute__((address_space(3))) void*)(region + c * 16), 16, 0, 0);
    }
}

// ---------------- bf16 GEMM (out-proj): 128^2 tile, 4-phase pipelined schedule -------
// Port of the proven qkv 4-phase schedule: counted vmcnt (never 0 mid-loop), staging
// into regions whose readers drained >=1 barrier earlier, vmcnt->barrier->ds_read.
__global__ __launch_bounds__(256, 2) void gemm_bt(const unsigned short* __restrict__ A,
                                                  const unsigned short* __restrict__ Bm,
                                                  float* __restrict__ C,
                                                  int M, int N, int K) {
    __shared__ char smem[65536];   // 2 x { A[128][64] 16KB, B[128][64] 16KB }
    int nt = K >> 6;
    int tid = threadIdx.x;
    int w = tid >> 6, lane = tid & 63, quad = lane >> 4, l15 = lane & 15;
    int wr = w >> 1, wc = w & 1;   // 2x2 wave grid; per-wave C = 64 x 64
    int rowBase = blockIdx.y * 128, colBase = blockIdx.x * 128;
    facc4 acc[4][4];
#pragma unroll
    for (int i = 0; i < 4; i++)
#pragma unroll
        for (int j = 0; j < 4; j++) acc[i][j] = facc4{0.f, 0.f, 0.f, 0.f};

    char* b0A = smem;          char* b0B = smem + 16384;
    char* b1A = smem + 32768;  char* b1B = smem + 49152;
    // prologue: tile0 full (8 loads), then B(1)h0, A(1)h0, A(1)h1 (6 loads)
    stage_half_bt(A,  rowBase, 0,  b0A, 0, tid, K);
    stage_half_bt(A,  rowBase, 0,  b0A, 1, tid, K);
    stage_half_bt(Bm, colBase, 0,  b0B, 0, tid, K);
    stage_half_bt(Bm, colBase, 0,  b0B, 1, tid, K);
    stage_half_bt(Bm, colBase, 64, b1B, 0, tid, K);
    stage_half_bt(A,  rowBase, 64, b1A, 0, tid, K);
    stage_half_bt(A,  rowBase, 64, b1A, 1, tid, K);
    asm volatile("s_waitcnt vmcnt(6)" ::: "memory");   // tile0 landed (this wave)
    __builtin_amdgcn_s_barrier();                      // ...and all other waves too

    bfrag8 a01[2][2], a23[2][2], b01[2][2], b23[2][2];
#pragma unroll
    for (int m = 0; m < 2; m++)
#pragma unroll
        for (int kh = 0; kh < 2; kh++) {
            int row = wr * 64 + m * 16 + l15;
            int ch = (kh * 4 + quad) ^ (row & 7);
            a01[m][kh] = *(const bfrag8*)(b0A + row * 128 + ch * 16);
        }
#pragma unroll
    for (int n = 0; n < 2; n++)
#pragma unroll
        for (int kh = 0; kh < 2; kh++) {
            int row = wc * 64 + n * 16 + l15;
            int ch = (kh * 4 + quad) ^ (row & 7);
            b01[n][kh] = *(const bfrag8*)(b0B + row * 128 + ch * 16);
        }

#pragma unroll 1
    for (int t = 0; t < nt; t++) {
        __builtin_amdgcn_sched_barrier(0);
        char* bA = smem + (t & 1) * 32768;
        char* bB = bA + 16384;
        char* oA = smem + ((t & 1) ^ 1) * 32768;
        char* oB = oA + 16384;
        int k1 = (t + 1) * 64, k2 = (t + 2) * 64;

        // ---- P1: read b23(t); stage B(t+1)h1 -> other buf; MFMA a01 x b01
#pragma unroll
        for (int n = 0; n < 2; n++)
#pragma unroll
            for (int kh = 0; kh < 2; kh++) {
                int row = wc * 64 + (2 + n) * 16 + l15;
                int ch = (kh * 4 + quad) ^ (row & 7);
                b23[n][kh] = *(const bfrag8*)(bB + row * 128 + ch * 16);
            }
        if (t + 1 < nt) stage_half_bt(Bm, colBase, k1, oB, 1, tid, K);
        __builtin_amdgcn_sched_barrier(0);
        __builtin_amdgcn_s_barrier();
        __builtin_amdgcn_s_setprio(1);
#pragma unroll
        for (int m = 0; m < 2; m++)
#pragma unroll
            for (int n = 0; n < 2; n++)
#pragma unroll
                for (int kh = 0; kh < 2; kh++)
                    acc[m][n] = __builtin_amdgcn_mfma_f32_16x16x32_bf16(a01[m][kh], b01[n][kh], acc[m][n], 0, 0, 0);
        __builtin_amdgcn_s_setprio(0);
        __builtin_amdgcn_s_barrier();

        // ---- P2: read a23(t); MFMA a01 x b23
#pragma unroll
        for (int m = 0; m < 2; m++)
#pragma unroll
            for (int kh = 0; kh < 2; kh++) {
                int row = wr * 64 + (2 + m) * 16 + l15;
                int ch = (kh * 4 + quad) ^ (row & 7);
                a23[m][kh] = *(const bfrag8*)(bA + row * 128 + ch * 16);
            }
        __builtin_amdgcn_sched_barrier(0);
        __builtin_amdgcn_s_barrier();
        __builtin_amdgcn_s_setprio(1);
#pragma unroll
        for (int m = 0; m < 2; m++)
#pragma unroll
            for (int n = 0; n < 2; n++)
#pragma unroll
                for (int kh = 0; kh < 2; kh++)
                    acc[m][2 + n] = __builtin_amdgcn_mfma_f32_16x16x32_bf16(a01[m][kh], b23[n][kh], acc[m][2 + n], 0, 0, 0);
        __builtin_amdgcn_s_setprio(0);
        __builtin_amdgcn_s_barrier();

        // ---- P3: stage B(t+2)h0 -> current bB (readers drained >=1 barrier ago);
        //          MFMA a23 x b23
        if (t + 2 < nt) stage_half_bt(Bm, colBase, k2, bB, 0, tid, K);
        __builtin_amdgcn_sched_barrier(0);
        __builtin_amdgcn_s_barrier();
        __builtin_amdgcn_s_setprio(1);
#pragma unroll
        for (int m = 0; m < 2; m++)
#pragma unroll
            for (int n = 0; n < 2; n++)
#pragma unroll
                for (int kh = 0; kh < 2; kh++)
                    acc[2 + m][2 + n] = __builtin_amdgcn_mfma_f32_16x16x32_bf16(a23[m][kh], b23[n][kh], acc[2 + m][2 + n], 0, 0, 0);
        __builtin_amdgcn_s_setprio(0);
        __builtin_amdgcn_s_barrier();

        // ---- P4: stage A(t+2) -> current bA; counted vmcnt -> barrier (tile t+1
        //          landed on ALL waves); MFMA a23 x b01; THEN reload a01/b01(t+1).
        if (t + 2 < nt) {
            stage_half_bt(A, rowBase, k2, bA, 0, tid, K);
            stage_half_bt(A, rowBase, k2, bA, 1, tid, K);
            asm volatile("s_waitcnt vmcnt(6)" ::: "memory");  // leaves {B(t+2)h0, A(t+2)}
        } else if (t + 1 < nt) {
            asm volatile("s_waitcnt vmcnt(0)" ::: "memory");  // last prefetch: drain all
        }
        __builtin_amdgcn_sched_barrier(0);
        __builtin_amdgcn_s_barrier();
        __builtin_amdgcn_s_setprio(1);
#pragma unroll
        for (int m = 0; m < 2; m++)
#pragma unroll
            for (int n = 0; n < 2; n++)
#pragma unroll
                for (int kh = 0; kh < 2; kh++)
                    acc[2 + m][n] = __builtin_amdgcn_mfma_f32_16x16x32_bf16(a23[m][kh], b01[n][kh], acc[2 + m][n], 0, 0, 0);
        __builtin_amdgcn_s_setprio(0);
        if (t + 1 < nt) {
#pragma unroll
            for (int m = 0; m < 2; m++)
#pragma unroll
                for (int kh = 0; kh < 2; kh++) {
                    int row = wr * 64 + m * 16 + l15;
                    int ch = (kh * 4 + quad) ^ (row & 7);
                    a01[m][kh] = *(const bfrag8*)(oA + row * 128 + ch * 16);
                }
#pragma unroll
            for (int n = 0; n < 2; n++)
#pragma unroll
                for (int kh = 0; kh < 2; kh++) {
                    int row = wc * 64 + n * 16 + l15;
                    int ch = (kh * 4 + quad) ^ (row & 7);
                    b01[n][kh] = *(const bfrag8*)(oB + row * 128 + ch * 16);
                }
        }
        __builtin_amdgcn_s_barrier();
    }

#pragma unroll
    for (int i = 0; i < 4; i++)
#pragma unroll
        for (int j = 0; j < 4; j++)
#pragma unroll
            for (int r = 0; r < 4; r++) {
                int row = rowBase + wr * 64 + i * 16 + quad * 4 + r;
                int col = colBase + wc * 64 + j * 16 + l15;
                C[(size_t)row * N + col] = acc[i][j][r];
            }
}

// ---------------- fused QKV GEMM (256^2 4-phase — R3 schedule, verified) -------------
// All cross-wave LDS reads obey: vmcnt(N) -> s_barrier -> ds_read (never read between
// a wave's own vmcnt and the barrier: other waves' staging may not have landed).
__global__ __launch_bounds__(512, 2) void gemm_qkv_fused(const unsigned short* __restrict__ A,
                                                         const unsigned short* __restrict__ Bm,
                                                         const float* __restrict__ qw,
                                                         const float* __restrict__ kw,
                                                         const float* __restrict__ lut,
                                                         unsigned short* __restrict__ q_bf,
                                                         unsigned short* __restrict__ k_bf,
                                                         _Float16* __restrict__ vT) {
    __shared__ char smem[131072];   // 2 x { A[256][64] 32KB, B[256][64] 32KB }
    const int NT = 32;              // K tiles of 64
    int tid = threadIdx.x;
    int w = tid >> 6, lane = tid & 63, quad = lane >> 4, l15 = lane & 15;
    int wr = w >> 2, wc = w & 3;    // 2 x 4 wave grid; per-wave C = 128 x 64
    int u = ((blockIdx.x & 7) << 5) | (blockIdx.x >> 3);
    int bx = u & 15, by = u >> 4;
    int rowBase = by * 256, colBase = bx * 256;

    facc4 acc[8][4];
#pragma unroll
    for (int m = 0; m < 8; m++)
#pragma unroll
        for (int n = 0; n < 4; n++) acc[m][n] = facc4{0.f, 0.f, 0.f, 0.f};

    char* b0A = smem;           char* b0B = smem + 32768;
    char* b1A = smem + 65536;   char* b1B = smem + 98304;
    // prologue: tile0 full (8 loads), then B(1)h0, A(1)h0, A(1)h1 (6 loads)
    stage_half(A,  rowBase, 0,  b0A, 0, tid);
    stage_half(A,  rowBase, 0,  b0A, 1, tid);
    stage_half(Bm, colBase, 0,  b0B, 0, tid);
    stage_half(Bm, colBase, 0,  b0B, 1, tid);
    stage_half(Bm, colBase, 64, b1B, 0, tid);
    stage_half(A,  rowBase, 64, b1A, 0, tid);
    stage_half(A,  rowBase, 64, b1A, 1, tid);
    asm volatile("s_waitcnt vmcnt(6)" ::: "memory");   // tile0 landed (this wave)
    __builtin_amdgcn_s_barrier();                      // ...and all other waves too

    bfrag8 a03[4][2], a47[4][2], b01[2][2], b23[2][2];
    // preload P1(0) operands (safe: after barrier)
#pragma unroll
    for (int m = 0; m < 4; m++)
#pragma unroll
        for (int kh = 0; kh < 2; kh++) {
            int row = wr * 128 + m * 16 + l15;
            int ch = (kh * 4 + quad) ^ (row & 7);
            a03[m][kh] = *(const bfrag8*)(b0A + row * 128 + ch * 16);
        }
#pragma unroll
    for (int n = 0; n < 2; n++)
#pragma unroll
        for (int kh = 0; kh < 2; kh++) {
            int row = wc * 64 + n * 16 + l15;
            int ch = (kh * 4 + quad) ^ (row & 7);
            b01[n][kh] = *(const bfrag8*)(b0B + row * 128 + ch * 16);
        }

#pragma unroll 1
    for (int t = 0; t < NT; t++) {
        __builtin_amdgcn_sched_barrier(0);
        char* bA = smem + (t & 1) * 65536;
        char* bB = bA + 32768;
        char* oA = smem + ((t & 1) ^ 1) * 65536;
        char* oB = oA + 32768;
        int k1 = (t + 1) * 64, k2 = (t + 2) * 64;

        // ---- P1: read b23(t); stage B(t+1)h1 -> other buf; MFMA m03 x b01
#pragma unroll
        for (int n = 0; n < 2; n++)
#pragma unroll
            for (int kh = 0; kh < 2; kh++) {
                int row = wc * 64 + (2 + n) * 16 + l15;
                int ch = (kh * 4 + quad) ^ (row & 7);
                b23[n][kh] = *(const bfrag8*)(bB + row * 128 + ch * 16);
            }
        if (t + 1 < NT) stage_half(Bm, colBase, k1, oB, 1, tid);
        __builtin_amdgcn_sched_barrier(0);
        __builtin_amdgcn_s_barrier();
        __builtin_amdgcn_s_setprio(1);
#pragma unroll
        for (int m = 0; m < 4; m++)
#pragma unroll
            for (int n = 0; n < 2; n++)
#pragma unroll
                for (int kh = 0; kh < 2; kh++)
                    acc[m][n] = __builtin_amdgcn_mfma_f32_16x16x32_bf16(a03[m][kh], b01[n][kh], acc[m][n], 0, 0, 0);
        __builtin_amdgcn_s_setprio(0);
        __builtin_amdgcn_s_barrier();

        // ---- P2: read a47(t); MFMA m03 x b23
#pragma unroll
        for (int m = 0; m < 4; m++)
#pragma unroll
            for (int kh = 0; kh < 2; kh++) {
                int row = wr * 128 + (4 + m) * 16 + l15;
                int ch = (kh * 4 + quad) ^ (row & 7);
                a47[m][kh] = *(const bfrag8*)(bA + row * 128 + ch * 16);
            }
        __builtin_amdgcn_sched_barrier(0);
        __builtin_amdgcn_s_barrier();
        __builtin_amdgcn_s_setprio(1);
#pragma unroll
        for (int m = 0; m < 4; m++)
#pragma unroll
            for (int n = 0; n < 2; n++)
#pragma unroll
                for (int kh = 0; kh < 2; kh++)
                    acc[m][2 + n] = __builtin_amdgcn_mfma_f32_16x16x32_bf16(a03[m][kh], b23[n][kh], acc[m][2 + n], 0, 0, 0);
        __builtin_amdgcn_s_setprio(0);
        __builtin_amdgcn_s_barrier();

        // ---- P3: stage B(t+2)h0 -> current bB (its readers drained >=1 barrier ago);
        //          MFMA m47 x b23
        if (t + 2 < NT) stage_half(Bm, colBase, k2, bB, 0, tid);
        __builtin_amdgcn_sched_barrier(0);
        __builtin_amdgcn_s_barrier();
        __builtin_amdgcn_s_setprio(1);
#pragma unroll
        for (int m = 0; m < 4; m++)
#pragma unroll
            for (int n = 0; n < 2; n++)
#pragma unroll
                for (int kh = 0; kh < 2; kh++)
                    acc[4 + m][2 + n] = __builtin_amdgcn_mfma_f32_16x16x32_bf16(a47[m][kh], b23[n][kh], acc[4 + m][2 + n], 0, 0, 0);
        __builtin_amdgcn_s_setprio(0);
        __builtin_amdgcn_s_barrier();

        // ---- P4: stage A(t+2) -> current bA; counted vmcnt -> barrier (tile t+1
        //          landed on ALL waves); MFMA m47 x b01; THEN reload a03/b01(t+1).
        if (t + 2 < NT) {
            stage_half(A, rowBase, k2, bA, 0, tid);
            stage_half(A, rowBase, k2, bA, 1, tid);
            asm volatile("s_waitcnt vmcnt(6)" ::: "memory");  // leaves {B(t+2)h0, A(t+2)}
        } else if (t + 1 < NT) {
            asm volatile("s_waitcnt vmcnt(0)" ::: "memory");  // last prefetch: drain all
        }
        __builtin_amdgcn_sched_barrier(0);
        __builtin_amdgcn_s_barrier();
        __builtin_amdgcn_s_setprio(1);
#pragma unroll
        for (int m = 0; m < 4; m++)
#pragma unroll
            for (int n = 0; n < 2; n++)
#pragma unroll
                for (int kh = 0; kh < 2; kh++)
                    acc[4 + m][n] = __builtin_amdgcn_mfma_f32_16x16x32_bf16(a47[m][kh], b01[n][kh], acc[4 + m][n], 0, 0, 0);
        __builtin_amdgcn_s_setprio(0);
        if (t + 1 < NT) {
#pragma unroll
            for (int m = 0; m < 4; m++)
#pragma unroll
                for (int kh = 0; kh < 2; kh++) {
                    int row = wr * 128 + m * 16 + l15;
                    int ch = (kh * 4 + quad) ^ (row & 7);
                    a03[m][kh] = *(const bfrag8*)(oA + row * 128 + ch * 16);
                }
#pragma unroll
            for (int n = 0; n < 2; n++)
#pragma unroll
                for (int kh = 0; kh < 2; kh++) {
                    int row = wc * 64 + n * 16 + l15;
                    int ch = (kh * 4 + quad) ^ (row & 7);
                    b01[n][kh] = *(const bfrag8*)(oB + row * 128 + ch * 16);
                }
        }
        __builtin_amdgcn_s_barrier();
    }

    // ================= epilogues =================
    if (bx >= 12) {
        // ---- V: fp32 acc -> fp16 tiled layout, direct from regs ----
        int hv = (bx - 12) * 2 + (wc >> 1);
#pragma unroll
        for (int half = 0; half < 2; half++) {
            int gt0 = rowBase + wr * 128 + half * 64;
            int bb = gt0 >> 11, t64 = (gt0 & 2047) >> 6;
            _Float16* vbase = vT + ((size_t)(bb * 8 + hv) * 32 + t64) * 8192;
#pragma unroll
            for (int mm = 0; mm < 4; mm++) {
                int kcp = mm >> 1, hh = mm & 1;
#pragma unroll
                for (int n = 0; n < 4; n++) {
                    int dblk = (wc & 1) * 4 + n;
                    f16x4 pv;
#pragma unroll
                    for (int r = 0; r < 4; r++) pv[r] = (_Float16)acc[half * 4 + mm][n][r];
                    *(f16x4*)(vbase + (((dblk * 2 + kcp) * 64 + quad * 16 + l15) * 8) + hh * 4) = pv;
                }
            }
        }
        return;
    }

    // ---- Q/K: RMSNorm (wave-pair via LDS) + RoPE(LUT) + relayout ----
    const float* wn = (bx < 8) ? qw : kw;
    const float osc = (bx < 8) ? (0.08838834764831845f * 1.4426950408889634f) : 1.0f;
    float* sums = (float*)smem;      // [4 wc][256 rows] partial sum-of-squares
#pragma unroll
    for (int m = 0; m < 8; m++)
#pragma unroll
        for (int r = 0; r < 4; r++) {
            float s = 0.f;
#pragma unroll
            for (int n = 0; n < 4; n++) s += acc[m][n][r] * acc[m][n][r];
            s += __shfl_xor(s, 1); s += __shfl_xor(s, 2);
            s += __shfl_xor(s, 4); s += __shfl_xor(s, 8);
            if (l15 == 0) sums[wc * 256 + wr * 128 + m * 16 + quad * 4 + r] = s;
        }
    __syncthreads();
    int hw = wc >> 1;                 // head within block (0/1)
    float inv[8][4];
#pragma unroll
    for (int m = 0; m < 8; m++)
#pragma unroll
        for (int r = 0; r < 4; r++) {
            int row = wr * 128 + m * 16 + quad * 4 + r;
            float tot = sums[(2 * hw) * 256 + row] + sums[(2 * hw + 1) * 256 + row];
            inv[m][r] = rsqrtf(tot * (1.0f / 128.0f) + 1e-6f);
        }
    __syncthreads();
    // normalized bf16 head tiles: [256][128] with 16B-granule XOR swizzle, reuse dbuf LDS
    unsigned short* tileb = (unsigned short*)(smem + hw * 65536);
    float wcol[4];
#pragma unroll
    for (int n = 0; n < 4; n++) wcol[n] = wn[(wc & 1) * 64 + n * 16 + l15];
#pragma unroll
    for (int m = 0; m < 8; m++)
#pragma unroll
        for (int r = 0; r < 4; r++) {
            int row = wr * 128 + m * 16 + quad * 4 + r;
            int sw = (row & 7) << 4;
#pragma unroll
            for (int n = 0; n < 4; n++) {
                int cb = ((wc & 1) * 64 + n * 16 + l15) * 2;
                *(unsigned short*)((char*)tileb + row * 256 + (cb ^ sw)) =
                    f2bf(acc[m][n][r] * inv[m][r] * wcol[n]);
            }
        }
    __syncthreads();
    {
        int row = tid >> 1, d0 = (tid & 1) * 32;
        int gt = rowBase + row;
        int tt = gt & 2047, bb = gt >> 11;
        const float* lc = lut + tt * 128;
        int sw = (row & 7) << 4;
#pragma unroll
        for (int hh2 = 0; hh2 < 2; hh2++) {
            const char* tb = (const char*)(smem + hh2 * 65536);
            unsigned short* qrow = 0; unsigned short* kplane = 0;
            if (bx < 8) qrow = q_bf + ((size_t)(bb * 16 + bx * 2 + hh2) * 2048 + tt) * 128;
            else        kplane = k_bf + (size_t)(bb * 8 + (bx - 8) * 2 + hh2) * 2048 * 128;
#pragma unroll
            for (int dc = 0; dc < 32; dc += 8) {
                int db = d0 + dc;
                us8 n0u = *(const us8*)(tb + row * 256 + ((2 * db) ^ sw));
                us8 n1u = *(const us8*)(tb + row * 256 + ((2 * db + 128) ^ sw));
                float4 cA = *(const float4*)(lc + db), cB = *(const float4*)(lc + db + 4);
                float4 sA = *(const float4*)(lc + 64 + db), sB = *(const float4*)(lc + 64 + db + 4);
                float cv[8] = {cA.x, cA.y, cA.z, cA.w, cB.x, cB.y, cB.z, cB.w};
                float sv[8] = {sA.x, sA.y, sA.z, sA.w, sB.x, sB.y, sB.z, sB.w};
                us8 p0, p1;
#pragma unroll
                for (int e = 0; e < 8; e++) {
                    float a0 = bf2f(n0u[e]), a1 = bf2f(n1u[e]);
                    p0[e] = f2bf((a0 * cv[e] - a1 * sv[e]) * osc);
                    p1[e] = f2bf((a1 * cv[e] + a0 * sv[e]) * osc);
                }
                if (bx < 8) {
                    *(us8*)(qrow + db) = p0;
                    *(us8*)(qrow + db + 64) = p1;
                } else {
                    *(us8*)(kplane + koff_tiled(tt, db)) = p0;
                    *(us8*)(kplane + koff_tiled(tt, db + 64)) = p1;
                }
            }
        }
    }
}

// ---------------- flash attention: 64-row q-blocks, 4 waves x 16 rows ----------------
// Occupancy fix (G1): LDS 32KB (K dbuf only; V read direct from L2 via the tiled
// layout's coalesced 16B/lane chunks) -> 4 blocks/CU x 4 waves = 4 waves/SIMD.
// Per-CU work is exactly constant: 2*(32-j) + 2*(j+1) = 66 keyblocks.
__global__ __launch_bounds__(256, 4) void attn_kernel(const unsigned short* __restrict__ q_bf,
                                                      const unsigned short* __restrict__ k_glob,
                                                      const _Float16* __restrict__ v_glob,
                                                      unsigned short* __restrict__ ctx) {
    __shared__ char smem[32768];   // K dbuf: 2 x 16KB
    int tid = threadIdx.x;
    int w = tid >> 6, lane = tid & 63, quad = lane >> 4, l15 = lane & 15;
    int bid = blockIdx.x;
    int u = bid & 511, halfg = bid >> 9;
    int j = u & 15, h = (u >> 4) & 15, b = (u >> 8) & 1;
    int qblk = halfg ? j : 31 - j;
    int hkv = h >> 1;
    int qb = qblk * 64;
    int qw0 = qb + w * 16;

    const unsigned short* qp = q_bf + (size_t)(b * Hq + h) * Tn * 128;
    const unsigned short* ktile = k_glob + (size_t)(b * HKVn + hkv) * 32 * 8192;
    const _Float16* vtile = v_glob + (size_t)(b * HKVn + hkv) * 32 * 8192;

    bfrag8 qf[4];
    {
        int row = qw0 + l15;
#pragma unroll
        for (int f = 0; f < 4; f++)
            qf[f] = *(const bfrag8*)(qp + (size_t)row * 128 + f * 32 + quad * 8);
    }

    facc4 o[8];
#pragma unroll
    for (int d = 0; d < 8; d++) o[d] = facc4{0.f, 0.f, 0.f, 0.f};
    float m0 = -__builtin_inff(), l0 = 0.f;

    int nkb = qblk + 1;
    // prologue: stage K(0) into buffer 0 (wave-uniform LDS base + lane*16)
#pragma unroll
    for (int i = 0; i < 4; i++) {
        const unsigned short* gk = ktile + (size_t)(i * 256 + tid) * 8;
        __builtin_amdgcn_global_load_lds((const __attribute__((address_space(1))) void*)gk,
            (__attribute__((address_space(3))) void*)(smem + i * 4096 + w * 1024), 16, 0, 0);
    }

    for (int ib = 0; ib < nkb; ib++) {
        int kb = ib * 64;
        __syncthreads();   // drains vmcnt(0): prefetch landed on all waves
        if (ib + 1 < nkb) {
            char* nb = smem + ((ib + 1) & 1) * 16384;
#pragma unroll
            for (int i = 0; i < 4; i++) {
                const unsigned short* gk = ktile + (size_t)(ib + 1) * 8192 + (i * 256 + tid) * 8;
                __builtin_amdgcn_global_load_lds((const __attribute__((address_space(1))) void*)gk,
                    (__attribute__((address_space(3))) void*)(nb + i * 4096 + w * 1024), 16, 0, 0);
            }
        }
        char* cb = smem + (ib & 1) * 16384;
        if (kb <= qw0 + 15) {
            facc4 s0[4];
#pragma unroll
            for (int kc = 0; kc < 4; kc++) {
                bfrag8 kf[4];
#pragma unroll
                for (int f = 0; f < 4; f++)
                    kf[f] = *(const bfrag8*)(cb + (((kc * 4 + f) * 64 + lane) << 4));
                facc4 a = facc4{0.f, 0.f, 0.f, 0.f};
#pragma unroll
                for (int f = 0; f < 4; f++)
                    a = __builtin_amdgcn_mfma_f32_16x16x32_bf16(kf[f], qf[f], a, 0, 0, 0);
                s0[kc] = a;
            }
            if (kb + 63 > qw0) {
                int q0 = qw0 + l15;
#pragma unroll
                for (int kc = 0; kc < 4; kc++)
#pragma unroll
                    for (int r = 0; r < 4; r++) {
                        int k = kb + kc * 16 + quad * 4 + r;
                        if (k > q0) s0[kc][r] = -__builtin_inff();
                    }
            }
            float mx0 = s0[0][0];
#pragma unroll
            for (int kc = 0; kc < 4; kc++)
#pragma unroll
                for (int r = 0; r < 4; r++) mx0 = fmaxf(mx0, s0[kc][r]);
            mx0 = fmaxf(mx0, __shfl_xor(mx0, 16)); mx0 = fmaxf(mx0, __shfl_xor(mx0, 32));
            // defer-max (T13): skip O/l rescale when tile max didn't grow past THR=8
            if (!__all(mx0 - m0 <= 8.f)) {
                float mn0 = fmaxf(m0, mx0);
                float alpha0 = exp2f(m0 - mn0);
                m0 = mn0;
                l0 *= alpha0;
#pragma unroll
                for (int d = 0; d < 8; d++)
#pragma unroll
                    for (int r = 0; r < 4; r++) o[d][r] *= alpha0;
            }
            float rs0 = 0.f;
#pragma unroll
            for (int kc = 0; kc < 4; kc++)
#pragma unroll
                for (int r = 0; r < 4; r++) {
                    s0[kc][r] = exp2f(s0[kc][r] - m0); rs0 += s0[kc][r];
                }
            rs0 += __shfl_xor(rs0, 16); rs0 += __shfl_xor(rs0, 32);
            l0 += rs0;
            f16x4 pb[4];
#pragma unroll
            for (int kc = 0; kc < 4; kc++)
                pb[kc] = f16x4{(_Float16)s0[kc][0], (_Float16)s0[kc][1],
                               (_Float16)s0[kc][2], (_Float16)s0[kc][3]};
            const _Float16* vb = vtile + (size_t)ib * 8192;
#pragma unroll
            for (int kcp = 0; kcp < 2; kcp++)
#pragma unroll
                for (int dblk = 0; dblk < 8; dblk++) {
                    f16x8 vv = *(const f16x8*)(vb + (((dblk * 2 + kcp) * 64 + lane) << 3));
                    f16x4 a0 = f16x4{vv[0], vv[1], vv[2], vv[3]};
                    f16x4 a1 = f16x4{vv[4], vv[5], vv[6], vv[7]};
                    o[dblk] = __builtin_amdgcn_mfma_f32_16x16x16f16(a0, pb[kcp * 2],     o[dblk], 0, 0, 0);
                    o[dblk] = __builtin_amdgcn_mfma_f32_16x16x16f16(a1, pb[kcp * 2 + 1], o[dblk], 0, 0, 0);
                }
        }
    }
    float inv0 = 1.0f / l0;
    int q = qw0 + l15;
#pragma unroll
    for (int dblk = 0; dblk < 8; dblk++) {
        ushort4 st;
        st.x = f2bf(o[dblk][0] * inv0); st.y = f2bf(o[dblk][1] * inv0);
        st.z = f2bf(o[dblk][2] * inv0); st.w = f2bf(o[dblk][3] * inv0);
        *(ushort4*)(ctx + ((size_t)(b * Tn + q)) * 2048 + h * 128 + dblk * 16 + quad * 4) = st;
    }
}

extern "C" void kernel_launch(void* const* d_in, const int* in_sizes, int n_in,
                              void* d_out, int out_size, void* d_ws, size_t ws_size,
                              hipStream_t stream) {
    (void)in_sizes; (void)n_in; (void)out_size; (void)ws_size;
    const float* x  = (const float*)d_in[0];
    const float* wq = (const float*)d_in[1];
    const float* wk = (const float*)d_in[2];
    const float* wv = (const float*)d_in[3];
    const float* wo = (const float*)d_in[4];
    const float* qw = (const float*)d_in[5];
    const float* kw = (const float*)d_in[6];
    float* out = (float*)d_out;
    char* ws = (char*)d_ws;

    unsigned short* x_bf    = (unsigned short*)(ws);               // 16.78 MB
    unsigned short* wqkv_bf = (unsigned short*)(ws + 16777216);    // 16.78 MB
    unsigned short* wo_bf   = (unsigned short*)(ws + 33554432);    //  8.39 MB
    unsigned short* q_bf    = (unsigned short*)(ws + 41943040);    // 16.78 MB [B][H][T][128]
    unsigned short* k_bf    = (unsigned short*)(ws + 58720256);    //  8.39 MB tiled
    _Float16*       vT_f16  = (_Float16*)(ws + 67108864);          //  8.39 MB tiled fp16
    unsigned short* ctx_bf  = (unsigned short*)(ws + 75497472);    // 16.78 MB [4096][2048]
    float*          lut     = (float*)(ws + 92274688);             //  1.05 MB [2048][128]

    cvt_all<<<20992, 256, 0, stream>>>(x, wq, wk, wv, wo, x_bf, wqkv_bf, wo_bf, lut);
    gemm_qkv_fused<<<256, 512, 0, stream>>>(x_bf, wqkv_bf, qw, kw, lut, q_bf, k_bf, vT_f16);
    attn_kernel<<<1024, 256, 0, stream>>>(q_bf, k_bf, vT_f16, ctx_bf);
    gemm_bt<<<dim3(16, 32), 256, 0, stream>>>(ctx_bf, wo_bf, out, 4096, 2048, 2048);
}

// Round 8
// 304.925 us; speedup vs baseline: 1.1489x; 1.1489x over previous
//
#include <hip/hip_runtime.h>
#include <cstdint>

#define Hq 16
#define HKVn 8
#define DHn 128
#define Tn 2048
#define Bn 2
#define Dm 2048
#define BT (Bn*Tn)   // 4096

typedef __attribute__((ext_vector_type(8))) short bfrag8;   // 8 bf16 (4 VGPRs)
typedef __attribute__((ext_vector_type(4))) float facc4;    // 4 fp32 acc
typedef __attribute__((ext_vector_type(4))) _Float16 f16x4; // 4 fp16 (2 VGPRs)
typedef __attribute__((ext_vector_type(8))) _Float16 f16x8; // 8 fp16 (4 VGPRs)
typedef __attribute__((ext_vector_type(8))) unsigned short us8;

__device__ __forceinline__ unsigned short f2bf(float f) {
    union { float f; unsigned int u; } v; v.f = f;
    unsigned int u = v.u;
    unsigned int r = (u + 0x7FFFu + ((u >> 16) & 1u)) >> 16;
    return (unsigned short)r;
}
__device__ __forceinline__ float bf2f(unsigned short u) {
    union { unsigned int u; float f; } v; v.u = ((unsigned int)u) << 16;
    return v.f;
}

// ---------------- fused fp32 -> bf16 convert + RoPE cos/sin LUT ----------------
__global__ __launch_bounds__(256) void cvt_all(const float* __restrict__ x,
                                               const float* __restrict__ wq,
                                               const float* __restrict__ wk,
                                               const float* __restrict__ wv,
                                               const float* __restrict__ wo,
                                               unsigned short* __restrict__ x_bf,
                                               unsigned short* __restrict__ wqkv_bf,
                                               unsigned short* __restrict__ wo_bf,
                                               float* __restrict__ lut) {
    int i = blockIdx.x * 256 + threadIdx.x;   // float4 index, total 5242880
    if (i >= 5242880) {
        int ii = i - 5242880;                 // 0..131071
        int t = ii >> 6, d = ii & 63;
        float fr = exp2f(-(float)d * 0.3114307588956902f);
        float ang = (float)t * fr;
        float sv, cv;
        __sincosf(ang, &sv, &cv);
        lut[t * 128 + d] = cv;
        lut[t * 128 + 64 + d] = sv;
        return;
    }
    const float4* src; ushort4* dst;
    if (i < 2097152)      { src = (const float4*)x  + i;            dst = (ushort4*)x_bf + i; }
    else if (i < 3145728) { src = (const float4*)wq + (i-2097152);  dst = (ushort4*)wqkv_bf + (i-2097152); }
    else if (i < 3670016) { src = (const float4*)wk + (i-3145728);  dst = (ushort4*)wqkv_bf + 1048576 + (i-3145728); }
    else if (i < 4194304) { src = (const float4*)wv + (i-3670016);  dst = (ushort4*)wqkv_bf + 1572864 + (i-3670016); }
    else                  { src = (const float4*)wo + (i-4194304);  dst = (ushort4*)wo_bf + (i-4194304); }
    float4 v = *src;
    ushort4 y;
    y.x = f2bf(v.x); y.y = f2bf(v.y); y.z = f2bf(v.z); y.w = f2bf(v.w);
    *dst = y;
}

// K tiled-layout element offset within a (b,hkv) plane (attn-kernel K layout).
__device__ __forceinline__ size_t koff_tiled(int t, int d) {
    int kc = (t >> 4) & 3, l15 = t & 15;
    int f = d >> 5, qd = (d >> 3) & 3, j = d & 7;
    return (size_t)(t >> 6) * 8192 + ((((kc * 4 + f) * 64 + qd * 16 + l15) << 3) + j);
}

// ---------------- staging helpers (linear LDS dest, inverse-XOR-swizzled source) -----
__device__ __forceinline__ void stage_half(const unsigned short* __restrict__ g0,
                                           int rowBase, int k0, char* region, int h, int tid) {
#pragma unroll
    for (int s = 0; s < 2; s++) {
        int c = h * 1024 + s * 512 + tid;        // chunk index (16B units)
        int r = c >> 3;
        int kk = (c & 7) ^ (r & 7);
        const unsigned short* g = g0 + (size_t)(rowBase + r) * 2048 + k0 + kk * 8;
        __builtin_amdgcn_global_load_lds((const __attribute__((address_space(1))) void*)g,
            (__attribute__((address_space(3))) void*)(region + c * 16), 16, 0, 0);
    }
}

// 64-row half-tile for the 128^2 out-proj kernel (256 threads, 2 loads/thread)
__device__ __forceinline__ void stage_half_bt(const unsigned short* __restrict__ g0,
                                              int rowBase, int k0, char* region, int h,
                                              int tid, int K) {
#pragma unroll
    for (int s = 0; s < 2; s++) {
        int c = h * 512 + s * 256 + tid;         // chunk index within 16KB region
        int r = c >> 3;
        int kk = (c & 7) ^ (r & 7);
        const unsigned short* g = g0 + (size_t)(rowBase + r) * K + k0 + kk * 8;
        __builtin_amdgcn_global_load_lds((const __attribute__((address_space(1))) void*)g,
            (__attribute__((address_space(3))) void*)(region + c * 16), 16, 0, 0);
    }
}

// ---------------- bf16 GEMM (out-proj): 128^2 tile, 4-phase pipelined schedule -------
__global__ __launch_bounds__(256, 2) void gemm_bt(const unsigned short* __restrict__ A,
                                                  const unsigned short* __restrict__ Bm,
                                                  float* __restrict__ C,
                                                  int M, int N, int K) {
    __shared__ char smem[65536];   // 2 x { A[128][64] 16KB, B[128][64] 16KB }
    int nt = K >> 6;
    int tid = threadIdx.x;
    int w = tid >> 6, lane = tid & 63, quad = lane >> 4, l15 = lane & 15;
    int wr = w >> 1, wc = w & 1;   // 2x2 wave grid; per-wave C = 64 x 64
    int rowBase = blockIdx.y * 128, colBase = blockIdx.x * 128;
    facc4 acc[4][4];
#pragma unroll
    for (int i = 0; i < 4; i++)
#pragma unroll
        for (int j = 0; j < 4; j++) acc[i][j] = facc4{0.f, 0.f, 0.f, 0.f};

    char* b0A = smem;          char* b0B = smem + 16384;
    char* b1A = smem + 32768;  char* b1B = smem + 49152;
    stage_half_bt(A,  rowBase, 0,  b0A, 0, tid, K);
    stage_half_bt(A,  rowBase, 0,  b0A, 1, tid, K);
    stage_half_bt(Bm, colBase, 0,  b0B, 0, tid, K);
    stage_half_bt(Bm, colBase, 0,  b0B, 1, tid, K);
    stage_half_bt(Bm, colBase, 64, b1B, 0, tid, K);
    stage_half_bt(A,  rowBase, 64, b1A, 0, tid, K);
    stage_half_bt(A,  rowBase, 64, b1A, 1, tid, K);
    asm volatile("s_waitcnt vmcnt(6)" ::: "memory");   // tile0 landed (this wave)
    __builtin_amdgcn_s_barrier();                      // ...and all other waves too

    bfrag8 a01[2][2], a23[2][2], b01[2][2], b23[2][2];
#pragma unroll
    for (int m = 0; m < 2; m++)
#pragma unroll
        for (int kh = 0; kh < 2; kh++) {
            int row = wr * 64 + m * 16 + l15;
            int ch = (kh * 4 + quad) ^ (row & 7);
            a01[m][kh] = *(const bfrag8*)(b0A + row * 128 + ch * 16);
        }
#pragma unroll
    for (int n = 0; n < 2; n++)
#pragma unroll
        for (int kh = 0; kh < 2; kh++) {
            int row = wc * 64 + n * 16 + l15;
            int ch = (kh * 4 + quad) ^ (row & 7);
            b01[n][kh] = *(const bfrag8*)(b0B + row * 128 + ch * 16);
        }

#pragma unroll 1
    for (int t = 0; t < nt; t++) {
        __builtin_amdgcn_sched_barrier(0);
        char* bA = smem + (t & 1) * 32768;
        char* bB = bA + 16384;
        char* oA = smem + ((t & 1) ^ 1) * 32768;
        char* oB = oA + 16384;
        int k1 = (t + 1) * 64, k2 = (t + 2) * 64;

        // ---- P1: read b23(t); stage B(t+1)h1 -> other buf; MFMA a01 x b01
#pragma unroll
        for (int n = 0; n < 2; n++)
#pragma unroll
            for (int kh = 0; kh < 2; kh++) {
                int row = wc * 64 + (2 + n) * 16 + l15;
                int ch = (kh * 4 + quad) ^ (row & 7);
                b23[n][kh] = *(const bfrag8*)(bB + row * 128 + ch * 16);
            }
        if (t + 1 < nt) stage_half_bt(Bm, colBase, k1, oB, 1, tid, K);
        __builtin_amdgcn_sched_barrier(0);
        __builtin_amdgcn_s_barrier();
        __builtin_amdgcn_s_setprio(1);
#pragma unroll
        for (int m = 0; m < 2; m++)
#pragma unroll
            for (int n = 0; n < 2; n++)
#pragma unroll
                for (int kh = 0; kh < 2; kh++)
                    acc[m][n] = __builtin_amdgcn_mfma_f32_16x16x32_bf16(a01[m][kh], b01[n][kh], acc[m][n], 0, 0, 0);
        __builtin_amdgcn_s_setprio(0);
        __builtin_amdgcn_s_barrier();

        // ---- P2: read a23(t); MFMA a01 x b23
#pragma unroll
        for (int m = 0; m < 2; m++)
#pragma unroll
            for (int kh = 0; kh < 2; kh++) {
                int row = wr * 64 + (2 + m) * 16 + l15;
                int ch = (kh * 4 + quad) ^ (row & 7);
                a23[m][kh] = *(const bfrag8*)(bA + row * 128 + ch * 16);
            }
        __builtin_amdgcn_sched_barrier(0);
        __builtin_amdgcn_s_barrier();
        __builtin_amdgcn_s_setprio(1);
#pragma unroll
        for (int m = 0; m < 2; m++)
#pragma unroll
            for (int n = 0; n < 2; n++)
#pragma unroll
                for (int kh = 0; kh < 2; kh++)
                    acc[m][2 + n] = __builtin_amdgcn_mfma_f32_16x16x32_bf16(a01[m][kh], b23[n][kh], acc[m][2 + n], 0, 0, 0);
        __builtin_amdgcn_s_setprio(0);
        __builtin_amdgcn_s_barrier();

        // ---- P3: stage B(t+2)h0 -> current bB; MFMA a23 x b23
        if (t + 2 < nt) stage_half_bt(Bm, colBase, k2, bB, 0, tid, K);
        __builtin_amdgcn_sched_barrier(0);
        __builtin_amdgcn_s_barrier();
        __builtin_amdgcn_s_setprio(1);
#pragma unroll
        for (int m = 0; m < 2; m++)
#pragma unroll
            for (int n = 0; n < 2; n++)
#pragma unroll
                for (int kh = 0; kh < 2; kh++)
                    acc[2 + m][2 + n] = __builtin_amdgcn_mfma_f32_16x16x32_bf16(a23[m][kh], b23[n][kh], acc[2 + m][2 + n], 0, 0, 0);
        __builtin_amdgcn_s_setprio(0);
        __builtin_amdgcn_s_barrier();

        // ---- P4: stage A(t+2) -> current bA; counted vmcnt -> barrier; MFMA a23 x b01;
        //          THEN reload a01/b01(t+1).
        if (t + 2 < nt) {
            stage_half_bt(A, rowBase, k2, bA, 0, tid, K);
            stage_half_bt(A, rowBase, k2, bA, 1, tid, K);
            asm volatile("s_waitcnt vmcnt(6)" ::: "memory");  // leaves {B(t+2)h0, A(t+2)}
        } else if (t + 1 < nt) {
            asm volatile("s_waitcnt vmcnt(0)" ::: "memory");  // last prefetch: drain all
        }
        __builtin_amdgcn_sched_barrier(0);
        __builtin_amdgcn_s_barrier();
        __builtin_amdgcn_s_setprio(1);
#pragma unroll
        for (int m = 0; m < 2; m++)
#pragma unroll
            for (int n = 0; n < 2; n++)
#pragma unroll
                for (int kh = 0; kh < 2; kh++)
                    acc[2 + m][n] = __builtin_amdgcn_mfma_f32_16x16x32_bf16(a23[m][kh], b01[n][kh], acc[2 + m][n], 0, 0, 0);
        __builtin_amdgcn_s_setprio(0);
        if (t + 1 < nt) {
#pragma unroll
            for (int m = 0; m < 2; m++)
#pragma unroll
                for (int kh = 0; kh < 2; kh++) {
                    int row = wr * 64 + m * 16 + l15;
                    int ch = (kh * 4 + quad) ^ (row & 7);
                    a01[m][kh] = *(const bfrag8*)(oA + row * 128 + ch * 16);
                }
#pragma unroll
            for (int n = 0; n < 2; n++)
#pragma unroll
                for (int kh = 0; kh < 2; kh++) {
                    int row = wc * 64 + n * 16 + l15;
                    int ch = (kh * 4 + quad) ^ (row & 7);
                    b01[n][kh] = *(const bfrag8*)(oB + row * 128 + ch * 16);
                }
        }
        __builtin_amdgcn_s_barrier();
    }

#pragma unroll
    for (int i = 0; i < 4; i++)
#pragma unroll
        for (int j = 0; j < 4; j++)
#pragma unroll
            for (int r = 0; r < 4; r++) {
                int row = rowBase + wr * 64 + i * 16 + quad * 4 + r;
                int col = colBase + wc * 64 + j * 16 + l15;
                C[(size_t)row * N + col] = acc[i][j][r];
            }
}

// ---------------- fused QKV GEMM (256^2 4-phase — R3 schedule, verified) -------------
__global__ __launch_bounds__(512, 2) void gemm_qkv_fused(const unsigned short* __restrict__ A,
                                                         const unsigned short* __restrict__ Bm,
                                                         const float* __restrict__ qw,
                                                         const float* __restrict__ kw,
                                                         const float* __restrict__ lut,
                                                         unsigned short* __restrict__ q_bf,
                                                         unsigned short* __restrict__ k_bf,
                                                         _Float16* __restrict__ vT) {
    __shared__ char smem[131072];   // 2 x { A[256][64] 32KB, B[256][64] 32KB }
    const int NT = 32;              // K tiles of 64
    int tid = threadIdx.x;
    int w = tid >> 6, lane = tid & 63, quad = lane >> 4, l15 = lane & 15;
    int wr = w >> 2, wc = w & 3;    // 2 x 4 wave grid; per-wave C = 128 x 64
    int u = ((blockIdx.x & 7) << 5) | (blockIdx.x >> 3);
    int bx = u & 15, by = u >> 4;
    int rowBase = by * 256, colBase = bx * 256;

    facc4 acc[8][4];
#pragma unroll
    for (int m = 0; m < 8; m++)
#pragma unroll
        for (int n = 0; n < 4; n++) acc[m][n] = facc4{0.f, 0.f, 0.f, 0.f};

    char* b0A = smem;           char* b0B = smem + 32768;
    char* b1A = smem + 65536;   char* b1B = smem + 98304;
    stage_half(A,  rowBase, 0,  b0A, 0, tid);
    stage_half(A,  rowBase, 0,  b0A, 1, tid);
    stage_half(Bm, colBase, 0,  b0B, 0, tid);
    stage_half(Bm, colBase, 0,  b0B, 1, tid);
    stage_half(Bm, colBase, 64, b1B, 0, tid);
    stage_half(A,  rowBase, 64, b1A, 0, tid);
    stage_half(A,  rowBase, 64, b1A, 1, tid);
    asm volatile("s_waitcnt vmcnt(6)" ::: "memory");   // tile0 landed (this wave)
    __builtin_amdgcn_s_barrier();                      // ...and all other waves too

    bfrag8 a03[4][2], a47[4][2], b01[2][2], b23[2][2];
#pragma unroll
    for (int m = 0; m < 4; m++)
#pragma unroll
        for (int kh = 0; kh < 2; kh++) {
            int row = wr * 128 + m * 16 + l15;
            int ch = (kh * 4 + quad) ^ (row & 7);
            a03[m][kh] = *(const bfrag8*)(b0A + row * 128 + ch * 16);
        }
#pragma unroll
    for (int n = 0; n < 2; n++)
#pragma unroll
        for (int kh = 0; kh < 2; kh++) {
            int row = wc * 64 + n * 16 + l15;
            int ch = (kh * 4 + quad) ^ (row & 7);
            b01[n][kh] = *(const bfrag8*)(b0B + row * 128 + ch * 16);
        }

#pragma unroll 1
    for (int t = 0; t < NT; t++) {
        __builtin_amdgcn_sched_barrier(0);
        char* bA = smem + (t & 1) * 65536;
        char* bB = bA + 32768;
        char* oA = smem + ((t & 1) ^ 1) * 65536;
        char* oB = oA + 32768;
        int k1 = (t + 1) * 64, k2 = (t + 2) * 64;

        // ---- P1: read b23(t); stage B(t+1)h1 -> other buf; MFMA m03 x b01
#pragma unroll
        for (int n = 0; n < 2; n++)
#pragma unroll
            for (int kh = 0; kh < 2; kh++) {
                int row = wc * 64 + (2 + n) * 16 + l15;
                int ch = (kh * 4 + quad) ^ (row & 7);
                b23[n][kh] = *(const bfrag8*)(bB + row * 128 + ch * 16);
            }
        if (t + 1 < NT) stage_half(Bm, colBase, k1, oB, 1, tid);
        __builtin_amdgcn_sched_barrier(0);
        __builtin_amdgcn_s_barrier();
        __builtin_amdgcn_s_setprio(1);
#pragma unroll
        for (int m = 0; m < 4; m++)
#pragma unroll
            for (int n = 0; n < 2; n++)
#pragma unroll
                for (int kh = 0; kh < 2; kh++)
                    acc[m][n] = __builtin_amdgcn_mfma_f32_16x16x32_bf16(a03[m][kh], b01[n][kh], acc[m][n], 0, 0, 0);
        __builtin_amdgcn_s_setprio(0);
        __builtin_amdgcn_s_barrier();

        // ---- P2: read a47(t); MFMA m03 x b23
#pragma unroll
        for (int m = 0; m < 4; m++)
#pragma unroll
            for (int kh = 0; kh < 2; kh++) {
                int row = wr * 128 + (4 + m) * 16 + l15;
                int ch = (kh * 4 + quad) ^ (row & 7);
                a47[m][kh] = *(const bfrag8*)(bA + row * 128 + ch * 16);
            }
        __builtin_amdgcn_sched_barrier(0);
        __builtin_amdgcn_s_barrier();
        __builtin_amdgcn_s_setprio(1);
#pragma unroll
        for (int m = 0; m < 4; m++)
#pragma unroll
            for (int n = 0; n < 2; n++)
#pragma unroll
                for (int kh = 0; kh < 2; kh++)
                    acc[m][2 + n] = __builtin_amdgcn_mfma_f32_16x16x32_bf16(a03[m][kh], b23[n][kh], acc[m][2 + n], 0, 0, 0);
        __builtin_amdgcn_s_setprio(0);
        __builtin_amdgcn_s_barrier();

        // ---- P3: stage B(t+2)h0 -> current bB; MFMA m47 x b23
        if (t + 2 < NT) stage_half(Bm, colBase, k2, bB, 0, tid);
        __builtin_amdgcn_sched_barrier(0);
        __builtin_amdgcn_s_barrier();
        __builtin_amdgcn_s_setprio(1);
#pragma unroll
        for (int m = 0; m < 4; m++)
#pragma unroll
            for (int n = 0; n < 2; n++)
#pragma unroll
                for (int kh = 0; kh < 2; kh++)
                    acc[4 + m][2 + n] = __builtin_amdgcn_mfma_f32_16x16x32_bf16(a47[m][kh], b23[n][kh], acc[4 + m][2 + n], 0, 0, 0);
        __builtin_amdgcn_s_setprio(0);
        __builtin_amdgcn_s_barrier();

        // ---- P4: stage A(t+2) -> current bA; counted vmcnt -> barrier; MFMA m47 x b01;
        //          THEN reload a03/b01(t+1).
        if (t + 2 < NT) {
            stage_half(A, rowBase, k2, bA, 0, tid);
            stage_half(A, rowBase, k2, bA, 1, tid);
            asm volatile("s_waitcnt vmcnt(6)" ::: "memory");  // leaves {B(t+2)h0, A(t+2)}
        } else if (t + 1 < NT) {
            asm volatile("s_waitcnt vmcnt(0)" ::: "memory");  // last prefetch: drain all
        }
        __builtin_amdgcn_sched_barrier(0);
        __builtin_amdgcn_s_barrier();
        __builtin_amdgcn_s_setprio(1);
#pragma unroll
        for (int m = 0; m < 4; m++)
#pragma unroll
            for (int n = 0; n < 2; n++)
#pragma unroll
                for (int kh = 0; kh < 2; kh++)
                    acc[4 + m][n] = __builtin_amdgcn_mfma_f32_16x16x32_bf16(a47[m][kh], b01[n][kh], acc[4 + m][n], 0, 0, 0);
        __builtin_amdgcn_s_setprio(0);
        if (t + 1 < NT) {
#pragma unroll
            for (int m = 0; m < 4; m++)
#pragma unroll
                for (int kh = 0; kh < 2; kh++) {
                    int row = wr * 128 + m * 16 + l15;
                    int ch = (kh * 4 + quad) ^ (row & 7);
                    a03[m][kh] = *(const bfrag8*)(oA + row * 128 + ch * 16);
                }
#pragma unroll
            for (int n = 0; n < 2; n++)
#pragma unroll
                for (int kh = 0; kh < 2; kh++) {
                    int row = wc * 64 + n * 16 + l15;
                    int ch = (kh * 4 + quad) ^ (row & 7);
                    b01[n][kh] = *(const bfrag8*)(oB + row * 128 + ch * 16);
                }
        }
        __builtin_amdgcn_s_barrier();
    }

    // ================= epilogues =================
    if (bx >= 12) {
        // ---- V: fp32 acc -> fp16 tiled layout, direct from regs ----
        int hv = (bx - 12) * 2 + (wc >> 1);
#pragma unroll
        for (int half = 0; half < 2; half++) {
            int gt0 = rowBase + wr * 128 + half * 64;
            int bb = gt0 >> 11, t64 = (gt0 & 2047) >> 6;
            _Float16* vbase = vT + ((size_t)(bb * 8 + hv) * 32 + t64) * 8192;
#pragma unroll
            for (int mm = 0; mm < 4; mm++) {
                int kcp = mm >> 1, hh = mm & 1;
#pragma unroll
                for (int n = 0; n < 4; n++) {
                    int dblk = (wc & 1) * 4 + n;
                    f16x4 pv;
#pragma unroll
                    for (int r = 0; r < 4; r++) pv[r] = (_Float16)acc[half * 4 + mm][n][r];
                    *(f16x4*)(vbase + (((dblk * 2 + kcp) * 64 + quad * 16 + l15) * 8) + hh * 4) = pv;
                }
            }
        }
        return;
    }

    // ---- Q/K: RMSNorm (wave-pair via LDS) + RoPE(LUT) + relayout ----
    const float* wn = (bx < 8) ? qw : kw;
    const float osc = (bx < 8) ? (0.08838834764831845f * 1.4426950408889634f) : 1.0f;
    float* sums = (float*)smem;      // [4 wc][256 rows] partial sum-of-squares
#pragma unroll
    for (int m = 0; m < 8; m++)
#pragma unroll
        for (int r = 0; r < 4; r++) {
            float s = 0.f;
#pragma unroll
            for (int n = 0; n < 4; n++) s += acc[m][n][r] * acc[m][n][r];
            s += __shfl_xor(s, 1); s += __shfl_xor(s, 2);
            s += __shfl_xor(s, 4); s += __shfl_xor(s, 8);
            if (l15 == 0) sums[wc * 256 + wr * 128 + m * 16 + quad * 4 + r] = s;
        }
    __syncthreads();
    int hw = wc >> 1;                 // head within block (0/1)
    float inv[8][4];
#pragma unroll
    for (int m = 0; m < 8; m++)
#pragma unroll
        for (int r = 0; r < 4; r++) {
            int row = wr * 128 + m * 16 + quad * 4 + r;
            float tot = sums[(2 * hw) * 256 + row] + sums[(2 * hw + 1) * 256 + row];
            inv[m][r] = rsqrtf(tot * (1.0f / 128.0f) + 1e-6f);
        }
    __syncthreads();
    // normalized bf16 head tiles: [256][128] with 16B-granule XOR swizzle, reuse dbuf LDS
    unsigned short* tileb = (unsigned short*)(smem + hw * 65536);
    float wcol[4];
#pragma unroll
    for (int n = 0; n < 4; n++) wcol[n] = wn[(wc & 1) * 64 + n * 16 + l15];
#pragma unroll
    for (int m = 0; m < 8; m++)
#pragma unroll
        for (int r = 0; r < 4; r++) {
            int row = wr * 128 + m * 16 + quad * 4 + r;
            int sw = (row & 7) << 4;
#pragma unroll
            for (int n = 0; n < 4; n++) {
                int cb = ((wc & 1) * 64 + n * 16 + l15) * 2;
                *(unsigned short*)((char*)tileb + row * 256 + (cb ^ sw)) =
                    f2bf(acc[m][n][r] * inv[m][r] * wcol[n]);
            }
        }
    __syncthreads();
    {
        int row = tid >> 1, d0 = (tid & 1) * 32;
        int gt = rowBase + row;
        int tt = gt & 2047, bb = gt >> 11;
        const float* lc = lut + tt * 128;
        int sw = (row & 7) << 4;
#pragma unroll
        for (int hh2 = 0; hh2 < 2; hh2++) {
            const char* tb = (const char*)(smem + hh2 * 65536);
            unsigned short* qrow = 0; unsigned short* kplane = 0;
            if (bx < 8) qrow = q_bf + ((size_t)(bb * 16 + bx * 2 + hh2) * 2048 + tt) * 128;
            else        kplane = k_bf + (size_t)(bb * 8 + (bx - 8) * 2 + hh2) * 2048 * 128;
#pragma unroll
            for (int dc = 0; dc < 32; dc += 8) {
                int db = d0 + dc;
                us8 n0u = *(const us8*)(tb + row * 256 + ((2 * db) ^ sw));
                us8 n1u = *(const us8*)(tb + row * 256 + ((2 * db + 128) ^ sw));
                float4 cA = *(const float4*)(lc + db), cB = *(const float4*)(lc + db + 4);
                float4 sA = *(const float4*)(lc + 64 + db), sB = *(const float4*)(lc + 64 + db + 4);
                float cv[8] = {cA.x, cA.y, cA.z, cA.w, cB.x, cB.y, cB.z, cB.w};
                float sv[8] = {sA.x, sA.y, sA.z, sA.w, sB.x, sB.y, sB.z, sB.w};
                us8 p0, p1;
#pragma unroll
                for (int e = 0; e < 8; e++) {
                    float a0 = bf2f(n0u[e]), a1 = bf2f(n1u[e]);
                    p0[e] = f2bf((a0 * cv[e] - a1 * sv[e]) * osc);
                    p1[e] = f2bf((a1 * cv[e] + a0 * sv[e]) * osc);
                }
                if (bx < 8) {
                    *(us8*)(qrow + db) = p0;
                    *(us8*)(qrow + db + 64) = p1;
                } else {
                    *(us8*)(kplane + koff_tiled(tt, db)) = p0;
                    *(us8*)(kplane + koff_tiled(tt, db + 64)) = p1;
                }
            }
        }
    }
}

// ---------------- flash attention: 128-row q-blocks, 8 waves x 16 rows ---------------
// Occupancy fix done right (R7 post-mortem): grid-per-phase is pinned at 2 blocks/CU,
// so extra waves must come from within the block: 512 threads = 8 waves x 16 q-rows.
// 2 blocks/CU x 8 waves = 16 waves/CU = 4 waves/SIMD (R6 had 2). Same traffic, same
// K+V LDS dbuf (64KB), same heavy/light block pairing, same sync structure as R6.
__global__ __launch_bounds__(512, 4) void attn_kernel(const unsigned short* __restrict__ q_bf,
                                                      const unsigned short* __restrict__ k_glob,
                                                      const _Float16* __restrict__ v_glob,
                                                      unsigned short* __restrict__ ctx) {
    __shared__ char smem[65536];   // dbuf: K 16KB + V 16KB per buffer
    int tid = threadIdx.x;
    int w = tid >> 6, lane = tid & 63, quad = lane >> 4, l15 = lane & 15;
    int bid = blockIdx.x;
    int u = bid & 255, halfg = bid >> 8;
    int j = u & 7, h = (u >> 3) & 15, b = (u >> 7) & 1;
    int qblk = halfg ? j : 15 - j;
    int hkv = h >> 1;
    int qb = qblk * 128;
    int qw0 = qb + w * 16;         // wave w owns rows qw0..qw0+15

    const unsigned short* qp = q_bf + (size_t)(b * Hq + h) * Tn * 128;
    const unsigned short* ktile = k_glob + (size_t)(b * HKVn + hkv) * 32 * 8192;
    const _Float16* vtile = v_glob + (size_t)(b * HKVn + hkv) * 32 * 8192;

    bfrag8 qf[4];
    {
        int row = qw0 + l15;
#pragma unroll
        for (int f = 0; f < 4; f++)
            qf[f] = *(const bfrag8*)(qp + (size_t)row * 128 + f * 32 + quad * 8);
    }

    facc4 o[8];
#pragma unroll
    for (int d = 0; d < 8; d++) o[d] = facc4{0.f, 0.f, 0.f, 0.f};
    float m0 = -__builtin_inff(), l0 = 0.f;

    int nkb = qb / 64 + 2;
    // prologue: stage K(0)+V(0) into buffer 0 (512 threads: 2 iters each of 16B/lane)
#pragma unroll
    for (int i = 0; i < 2; i++) {
        const unsigned short* gk = ktile + (size_t)(i * 512 + tid) * 8;
        __builtin_amdgcn_global_load_lds((const __attribute__((address_space(1))) void*)gk,
            (__attribute__((address_space(3))) void*)(smem + i * 8192 + w * 1024), 16, 0, 0);
        const _Float16* gv = vtile + (size_t)(i * 512 + tid) * 8;
        __builtin_amdgcn_global_load_lds((const __attribute__((address_space(1))) void*)gv,
            (__attribute__((address_space(3))) void*)(smem + 16384 + i * 8192 + w * 1024), 16, 0, 0);
    }

    for (int ib = 0; ib < nkb; ib++) {
        int kb = ib * 64;
        __syncthreads();   // drains vmcnt(0): prefetch landed on all waves
        if (ib + 1 < nkb) {
            char* nb = smem + ((ib + 1) & 1) * 32768;
#pragma unroll
            for (int i = 0; i < 2; i++) {
                const unsigned short* gk = ktile + (size_t)(ib + 1) * 8192 + (i * 512 + tid) * 8;
                __builtin_amdgcn_global_load_lds((const __attribute__((address_space(1))) void*)gk,
                    (__attribute__((address_space(3))) void*)(nb + i * 8192 + w * 1024), 16, 0, 0);
                const _Float16* gv = vtile + (size_t)(ib + 1) * 8192 + (i * 512 + tid) * 8;
                __builtin_amdgcn_global_load_lds((const __attribute__((address_space(1))) void*)gv,
                    (__attribute__((address_space(3))) void*)(nb + 16384 + i * 8192 + w * 1024), 16, 0, 0);
            }
        }
        char* cb = smem + (ib & 1) * 32768;
        if (kb <= qw0 + 15) {
            facc4 s0[4];
#pragma unroll
            for (int kc = 0; kc < 4; kc++) {
                bfrag8 kf[4];
#pragma unroll
                for (int f = 0; f < 4; f++)
                    kf[f] = *(const bfrag8*)(cb + (((kc * 4 + f) * 64 + lane) << 4));
                facc4 a = facc4{0.f, 0.f, 0.f, 0.f};
#pragma unroll
                for (int f = 0; f < 4; f++)
                    a = __builtin_amdgcn_mfma_f32_16x16x32_bf16(kf[f], qf[f], a, 0, 0, 0);
                s0[kc] = a;
            }
            if (kb + 63 > qw0) {
                int q0 = qw0 + l15;
#pragma unroll
                for (int kc = 0; kc < 4; kc++)
#pragma unroll
                    for (int r = 0; r < 4; r++) {
                        int k = kb + kc * 16 + quad * 4 + r;
                        if (k > q0) s0[kc][r] = -__builtin_inff();
                    }
            }
            float mx0 = s0[0][0];
#pragma unroll
            for (int kc = 0; kc < 4; kc++)
#pragma unroll
                for (int r = 0; r < 4; r++) mx0 = fmaxf(mx0, s0[kc][r]);
            mx0 = fmaxf(mx0, __shfl_xor(mx0, 16)); mx0 = fmaxf(mx0, __shfl_xor(mx0, 32));
            // defer-max (T13): skip O/l rescale when tile max didn't grow past THR=8
            if (!__all(mx0 - m0 <= 8.f)) {
                float mn0 = fmaxf(m0, mx0);
                float alpha0 = exp2f(m0 - mn0);
                m0 = mn0;
                l0 *= alpha0;
#pragma unroll
                for (int d = 0; d < 8; d++)
#pragma unroll
                    for (int r = 0; r < 4; r++) o[d][r] *= alpha0;
            }
            float rs0 = 0.f;
#pragma unroll
            for (int kc = 0; kc < 4; kc++)
#pragma unroll
                for (int r = 0; r < 4; r++) {
                    s0[kc][r] = exp2f(s0[kc][r] - m0); rs0 += s0[kc][r];
                }
            rs0 += __shfl_xor(rs0, 16); rs0 += __shfl_xor(rs0, 32);
            l0 += rs0;
            f16x4 pb[4];
#pragma unroll
            for (int kc = 0; kc < 4; kc++)
                pb[kc] = f16x4{(_Float16)s0[kc][0], (_Float16)s0[kc][1],
                               (_Float16)s0[kc][2], (_Float16)s0[kc][3]};
#pragma unroll
            for (int kcp = 0; kcp < 2; kcp++)
#pragma unroll
                for (int dblk = 0; dblk < 8; dblk++) {
                    f16x8 vv = *(const f16x8*)(cb + 16384 + (((dblk * 2 + kcp) * 64 + lane) << 4));
                    f16x4 a0 = f16x4{vv[0], vv[1], vv[2], vv[3]};
                    f16x4 a1 = f16x4{vv[4], vv[5], vv[6], vv[7]};
                    o[dblk] = __builtin_amdgcn_mfma_f32_16x16x16f16(a0, pb[kcp * 2],     o[dblk], 0, 0, 0);
                    o[dblk] = __builtin_amdgcn_mfma_f32_16x16x16f16(a1, pb[kcp * 2 + 1], o[dblk], 0, 0, 0);
                }
        }
    }
    float inv0 = 1.0f / l0;
    int q = qw0 + l15;
#pragma unroll
    for (int dblk = 0; dblk < 8; dblk++) {
        ushort4 st;
        st.x = f2bf(o[dblk][0] * inv0); st.y = f2bf(o[dblk][1] * inv0);
        st.z = f2bf(o[dblk][2] * inv0); st.w = f2bf(o[dblk][3] * inv0);
        *(ushort4*)(ctx + ((size_t)(b * Tn + q)) * 2048 + h * 128 + dblk * 16 + quad * 4) = st;
    }
}

extern "C" void kernel_launch(void* const* d_in, const int* in_sizes, int n_in,
                              void* d_out, int out_size, void* d_ws, size_t ws_size,
                              hipStream_t stream) {
    (void)in_sizes; (void)n_in; (void)out_size; (void)ws_size;
    const float* x  = (const float*)d_in[0];
    const float* wq = (const float*)d_in[1];
    const float* wk = (const float*)d_in[2];
    const float* wv = (const float*)d_in[3];
    const float* wo = (const float*)d_in[4];
    const float* qw = (const float*)d_in[5];
    const float* kw = (const float*)d_in[6];
    float* out = (float*)d_out;
    char* ws = (char*)d_ws;

    unsigned short* x_bf    = (unsigned short*)(ws);               // 16.78 MB
    unsigned short* wqkv_bf = (unsigned short*)(ws + 16777216);    // 16.78 MB
    unsigned short* wo_bf   = (unsigned short*)(ws + 33554432);    //  8.39 MB
    unsigned short* q_bf    = (unsigned short*)(ws + 41943040);    // 16.78 MB [B][H][T][128]
    unsigned short* k_bf    = (unsigned short*)(ws + 58720256);    //  8.39 MB tiled
    _Float16*       vT_f16  = (_Float16*)(ws + 67108864);          //  8.39 MB tiled fp16
    unsigned short* ctx_bf  = (unsigned short*)(ws + 75497472);    // 16.78 MB [4096][2048]
    float*          lut     = (float*)(ws + 92274688);             //  1.05 MB [2048][128]

    cvt_all<<<20992, 256, 0, stream>>>(x, wq, wk, wv, wo, x_bf, wqkv_bf, wo_bf, lut);
    gemm_qkv_fused<<<256, 512, 0, stream>>>(x_bf, wqkv_bf, qw, kw, lut, q_bf, k_bf, vT_f16);
    attn_kernel<<<512, 512, 0, stream>>>(q_bf, k_bf, vT_f16, ctx_bf);
    gemm_bt<<<dim3(16, 32), 256, 0, stream>>>(ctx_bf, wo_bf, out, 4096, 2048, 2048);
}